// Round 4
// baseline (478.558 us; speedup 1.0000x reference)
//
#include <hip/hip_runtime.h>
#include <cstdint>
#include <cstddef>

#define NLAB 128
#define TT   512
#define BB   512
#define PAD_ 0
#define BOS_ 1
#define EOS_ 2

typedef float v2f __attribute__((ext_vector_type(2)));

// ---- mask dtype hedge: bool(1B) vs int32(4B) -------------------------------
__device__ __forceinline__ bool mask_is_i32(const unsigned char* m8) {
    return m8[1] == 0;   // mask[0][1] is always true; int32 high byte => 0
}
__device__ __forceinline__ bool mask_at(const unsigned char* m8, int idx, bool isi) {
    if (isi) return ((const int*)m8)[idx] != 0;
    return m8[idx] != 0;
}

// E column pair (rows 2i, 2i+1) as NAMED locals — no alloca, nothing for SROA
// to fail on (rounds 2/3: v2f array stayed in scratch -> 34MB spill traffic).
#define E_LOAD(i) \
    float e0_##i = __expf(tr[(2*(i)+0)*NLAB + j]); \
    float e1_##i = __expf(tr[(2*(i)+1)*NLAB + j]); \
    asm volatile("" : "+v"(e0_##i), "+v"(e1_##i)); \
    v2f E_##i; E_##i.x = e0_##i; E_##i.y = e1_##i;

#define MV(k4, a, b, accA, accB) { \
    const float4 pv = p4[k4]; \
    v2f plo; plo.x = pv.x; plo.y = pv.y; \
    v2f phi; phi.x = pv.z; phi.y = pv.w; \
    accA = __builtin_elementwise_fma(plo, E_##a, accA); \
    accB = __builtin_elementwise_fma(phi, E_##b, accB); }

// ---- forward + gold fused: one block (128 thr) per batch -------------------
__global__ __launch_bounds__(NLAB, 1)
__attribute__((amdgpu_waves_per_eu(1)))
void crf_forward(
        const float* __restrict__ feats,
        const int*   __restrict__ tags,
        const unsigned char* __restrict__ m8,
        const float* __restrict__ tr,
        float* __restrict__ gold_out,
        float* __restrict__ logZ_out) {
    const int b = blockIdx.x;
    const int j = threadIdx.x;
    const bool isi = mask_is_i32(m8);

    __shared__ __align__(16) float p_sh[2][NLAB];
    __shared__ float u3_sh[2];
    __shared__ float red[2], red2[2];
    __shared__ float gsh[2];
    __shared__ int   csh[2];

    const size_t fbase = (size_t)b * TT * NLAB;

    // ---- fused gold score + length ----
    float gpart = 0.f;
    int   cnt   = 0;
    #pragma unroll
    for (int tt = j; tt < TT; tt += NLAB) {
        const int idx = b * TT + tt;
        const bool mm = mask_at(m8, idx, isi);
        cnt += mm ? 1 : 0;
        const int tag = tags[idx];
        if (tt == 0) {
            gpart += feats[fbase + tag] + tr[BOS_ * NLAB + tag];
        } else if (mm) {
            gpart += feats[fbase + (size_t)tt * NLAB + tag]
                   + tr[tags[idx - 1] * NLAB + tag];
        }
    }
    #pragma unroll
    for (int off = 32; off > 0; off >>= 1) {
        gpart += __shfl_down(gpart, off, 64);
        cnt   += __shfl_down(cnt,   off, 64);
    }
    if ((j & 63) == 0) { gsh[j >> 6] = gpart; csh[j >> 6] = cnt; }

    // ---- E[:,j] -> 64 named v2f registers (128 VGPRs), asm-pinned ----
    E_LOAD(0)  E_LOAD(1)  E_LOAD(2)  E_LOAD(3)  E_LOAD(4)  E_LOAD(5)  E_LOAD(6)  E_LOAD(7)
    E_LOAD(8)  E_LOAD(9)  E_LOAD(10) E_LOAD(11) E_LOAD(12) E_LOAD(13) E_LOAD(14) E_LOAD(15)
    E_LOAD(16) E_LOAD(17) E_LOAD(18) E_LOAD(19) E_LOAD(20) E_LOAD(21) E_LOAD(22) E_LOAD(23)
    E_LOAD(24) E_LOAD(25) E_LOAD(26) E_LOAD(27) E_LOAD(28) E_LOAD(29) E_LOAD(30) E_LOAD(31)
    E_LOAD(32) E_LOAD(33) E_LOAD(34) E_LOAD(35) E_LOAD(36) E_LOAD(37) E_LOAD(38) E_LOAD(39)
    E_LOAD(40) E_LOAD(41) E_LOAD(42) E_LOAD(43) E_LOAD(44) E_LOAD(45) E_LOAD(46) E_LOAD(47)
    E_LOAD(48) E_LOAD(49) E_LOAD(50) E_LOAD(51) E_LOAD(52) E_LOAD(53) E_LOAD(54) E_LOAD(55)
    E_LOAD(56) E_LOAD(57) E_LOAD(58) E_LOAD(59) E_LOAD(60) E_LOAD(61) E_LOAD(62) E_LOAD(63)

    // ---- init ----
    float u = tr[BOS_ * NLAB + j] + feats[fbase + j];
    if (j == 3) u3_sh[0] = u;     // label 3 is always live (not PAD/BOS/EOS)
    __syncthreads();

    const int len = csh[0] + csh[1];   // >= 256 always
    if (j == 0) {
        const int last = tags[b * TT + (len - 1)];
        gold_out[b] = gsh[0] + gsh[1] + tr[last * NLAB + EOS_];
    }

    float norm = u3_sh[0];   // lagged normalizer, never -inf
    float C = 0.f;           // true fv = u + C

    // 4-deep feature prefetch ring
    float fr0 = feats[fbase + 1 * NLAB + j];
    float fr1 = feats[fbase + 2 * NLAB + j];
    float fr2 = feats[fbase + 3 * NLAB + j];
    float fr3 = feats[fbase + 4 * NLAB + j];

    for (int t = 1; t < len; ++t) {
        const float p = __expf(u - norm);
        C += norm;
        p_sh[t & 1][j] = p;
        const float ft = fr0;
        fr0 = fr1; fr1 = fr2; fr2 = fr3;
        const int tpre = (t + 5 < len) ? (t + 5) : (len - 1);
        fr3 = feats[fbase + (size_t)tpre * NLAB + j];
        __syncthreads();                       // the ONLY barrier per step
        const float nn = u3_sh[(t - 1) & 1];   // normalizer for step t+1

        // s_j = sum_k p[k] * E[k][j] out of register-resident E
        v2f acc0 = {0.f, 0.f}, acc1 = {0.f, 0.f}, acc2 = {0.f, 0.f}, acc3 = {0.f, 0.f};
        const float4* p4 = (const float4*)p_sh[t & 1];
        MV(0,  0,  1,  acc0, acc1) MV(1,  2,  3,  acc2, acc3)
        MV(2,  4,  5,  acc0, acc1) MV(3,  6,  7,  acc2, acc3)
        MV(4,  8,  9,  acc0, acc1) MV(5,  10, 11, acc2, acc3)
        MV(6,  12, 13, acc0, acc1) MV(7,  14, 15, acc2, acc3)
        MV(8,  16, 17, acc0, acc1) MV(9,  18, 19, acc2, acc3)
        MV(10, 20, 21, acc0, acc1) MV(11, 22, 23, acc2, acc3)
        MV(12, 24, 25, acc0, acc1) MV(13, 26, 27, acc2, acc3)
        MV(14, 28, 29, acc0, acc1) MV(15, 30, 31, acc2, acc3)
        MV(16, 32, 33, acc0, acc1) MV(17, 34, 35, acc2, acc3)
        MV(18, 36, 37, acc0, acc1) MV(19, 38, 39, acc2, acc3)
        MV(20, 40, 41, acc0, acc1) MV(21, 42, 43, acc2, acc3)
        MV(22, 44, 45, acc0, acc1) MV(23, 46, 47, acc2, acc3)
        MV(24, 48, 49, acc0, acc1) MV(25, 50, 51, acc2, acc3)
        MV(26, 52, 53, acc0, acc1) MV(27, 54, 55, acc2, acc3)
        MV(28, 56, 57, acc0, acc1) MV(29, 58, 59, acc2, acc3)
        MV(30, 60, 61, acc0, acc1) MV(31, 62, 63, acc2, acc3)
        const v2f accs = (acc0 + acc1) + (acc2 + acc3);
        const float s = accs.x + accs.y;       // 0 for dead columns -> -inf: ok

        u = __logf(s) + ft;
        if (j == 3) u3_sh[t & 1] = u;
        norm = nn;
    }

    // ---- logZ = C + logsumexp_j(u + tr[j, EOS]) ----
    const float v = u + tr[j * NLAB + EOS_];
    float m = v;
    #pragma unroll
    for (int off = 32; off > 0; off >>= 1)
        m = fmaxf(m, __shfl_xor(m, off, 64));
    if ((j & 63) == 0) red[j >> 6] = m;
    __syncthreads();
    m = fmaxf(red[0], red[1]);
    float e = __expf(v - m);
    #pragma unroll
    for (int off = 32; off > 0; off >>= 1)
        e += __shfl_xor(e, off, 64);
    if ((j & 63) == 0) red2[j >> 6] = e;
    __syncthreads();
    if (j == 0) logZ_out[b] = C + m + __logf(red2[0] + red2[1]);
}

// ---- final reduction: out = mean(logZ - gold) ------------------------------
__global__ void crf_finalize(const float* __restrict__ gold,
                             const float* __restrict__ logZ,
                             float* __restrict__ out) {
    __shared__ float sh[4];
    const int i = threadIdx.x;  // 256 threads
    float v = (logZ[i] - gold[i]) + (logZ[i + 256] - gold[i + 256]);
    #pragma unroll
    for (int off = 32; off > 0; off >>= 1)
        v += __shfl_xor(v, off, 64);
    if ((i & 63) == 0) sh[i >> 6] = v;
    __syncthreads();
    if (i == 0) out[0] = (sh[0] + sh[1] + sh[2] + sh[3]) * (1.0f / (float)BB);
}

extern "C" void kernel_launch(void* const* d_in, const int* in_sizes, int n_in,
                              void* d_out, int out_size, void* d_ws, size_t ws_size,
                              hipStream_t stream) {
    const float*         feats = (const float*)d_in[0];
    const int*           tags  = (const int*)d_in[1];
    const unsigned char* m8    = (const unsigned char*)d_in[2];
    const float*         tr    = (const float*)d_in[3];

    float* gold = (float*)d_ws;       // 512 floats
    float* logZ = gold + BB;          // 512 floats
    float* out  = (float*)d_out;

    hipLaunchKernelGGL(crf_forward,  dim3(BB), dim3(NLAB), 0, stream,
                       feats, tags, m8, tr, gold, logZ);
    hipLaunchKernelGGL(crf_finalize, dim3(1),  dim3(256),  0, stream,
                       gold, logZ, out);
}